// Round 3
// baseline (652.287 us; speedup 1.0000x reference)
//
#include <hip/hip_runtime.h>
#include <hip/hip_bf16.h>
#include <stdint.h>

// SSL hashed-sparse linear: out[M,N] = x[M,K] @ w_full[N,K]^T + bias
// w_full[n,k] = weight[n, h(n/32, k/32)*32 + k%32],
// h = ((kb*r0 + nb*r1 + r2) ^ r3) % num_red_kb   (uint32)
//
// fp32 in/out; compute in bf16 MFMA (threshold 0.165; absmax 0.03).
// ROUND-3: split-K x4, atomics epilogue (grid 1024).
// ROUND-4/5: raw s_barrier + lgkmcnt-only wait (counted vmcnt) -- NEUTRAL.
//   Post-mortem: stall is occupancy, not the barrier drain. VGPR_Count=116 is
//   arch-only; +64 acc AGPRs (unified file) = 180/wave -> 2 waves/SIMD =
//   2 blocks/CU (Occupancy 21% measured; round-1 clamped build 128 total ->
//   45% measured: model fits both).
// ROUND-6 (this): shrink state to fit 3 blocks/CU without spills:
//   (a) single-set A prefetch (drop a1/b1, -32 VGPR);
//   (b) B never touches LDS: W is 2MB = L2-resident, so per-wave B fragments
//       load直接 from global (coalesced 16 rows x 128B, wave-uniform hash),
//       issued one K-step early, cvt in-reg. Deletes half the DS traffic and
//       most of the 16.8M bank-conflict cycles.
//   __launch_bounds__(256,3): cap 170 unified = 106 arch (expected natural
//   ~95-105; NOT round-1's 116->64 crush).
// Predicted: Occupancy 21->~35%, conflicts 16.8M->~8M, dur 247->150-185us.

typedef __bf16 bf16x4_t __attribute__((ext_vector_type(4)));
typedef __bf16 bf16x8_t __attribute__((ext_vector_type(8)));
typedef float f32x4 __attribute__((ext_vector_type(4)));

#define BM 128
#define BN 128
#define BK 32
#define LDSK 40   // padded A row stride (bf16 elems); 80 B
#define KSPLIT 4

__global__ void init_out(float* __restrict__ Out, const float* __restrict__ Bias,
                         int N, int total4) {
  int i = blockIdx.x * blockDim.x + threadIdx.x;
  if (i < total4) {
    int idx = i << 2;
    int n = idx % N;                       // multiple of 4 since N%4==0
    *(f32x4*)(Out + idx) = *(const f32x4*)(Bias + n);
  }
}

// Raw workgroup barrier: LDS visibility only (lgkm drain; vmcnt stays counted).
__device__ __forceinline__ void wg_barrier_lds() {
  __builtin_amdgcn_sched_barrier(0);
  asm volatile("s_waitcnt lgkmcnt(0)" ::: "memory");
  __builtin_amdgcn_s_barrier();
  __builtin_amdgcn_sched_barrier(0);
}

__global__ __launch_bounds__(256, 3) void ssl_gemm(
    const float* __restrict__ X,       // [M,K]
    const float* __restrict__ W,       // [N,redK]
    const int* __restrict__ RN,        // [4]
    float* __restrict__ Out,           // [M,N], pre-seeded with bias
    int M, int N, int K, int redK, uint32_t numRedKb, int mTiles, int nTiles) {
  __shared__ __align__(16) __bf16 As[BM * LDSK];

  const uint32_t r0 = (uint32_t)RN[0], r1 = (uint32_t)RN[1];
  const uint32_t r2 = (uint32_t)RN[2], r3 = (uint32_t)RN[3];
  const uint32_t redMask = numRedKb - 1u;
  const bool pow2 = (numRedKb & (numRedKb - 1u)) == 0u;

  const int id = blockIdx.x;
  // id = m + mTiles*(n + nTiles*s); mTiles=64 (mult of 8) -> all blocks of an
  // m-tile share id%8 -> same XCD -> L2 reuse of the A chunk.
  const int mTile = id % mTiles;
  const int rest = id / mTiles;
  const int nTile = rest % nTiles;
  const int kChunk = rest / nTiles;      // 0..KSPLIT-1

  const int tid = threadIdx.x;
  const int wave = tid >> 6;
  const int lane = tid & 63;
  const int wm = wave >> 1, wn = wave & 1;  // 2x2 wave grid, each 64x64

  // A staging map: thread covers rows {i*32+lRow}, cols lCol..lCol+3
  const int lRow = tid >> 3;        // 0..31
  const int lCol = (tid & 7) << 2;  // 0,4,..,28
  const float* aBase = X + (size_t)(mTile * BM + lRow) * K + lCol;

  // B fragment map (direct from W, matches MFMA B-operand layout exactly as
  // the old LDS-staged read): lane holds row n = nTile*BN + wn*64 + ni*16 +
  // (lane&15), k-elems e0..e0+7 of the hashed 32-col block.
  const int r16 = lane & 15;
  const int e0 = (lane >> 4) << 3;  // 0,8,16,24
  const float* wBase = W + (size_t)(nTile * BN + wn * 64 + r16) * redK + e0;

  auto loadA = [&](int kb, f32x4* r) {
    const float* p = aBase + (size_t)kb * BK;
#pragma unroll
    for (int i = 0; i < 4; ++i)
      r[i] = *(const f32x4*)(p + (size_t)(i * 32) * K);
  };

  f32x4 bF[8];  // 4 frags x 8 floats/lane
  auto loadBf = [&](int kb) {
    const uint32_t kk = (uint32_t)kb * r0 + r2;
#pragma unroll
    for (int ni = 0; ni < 4; ++ni) {
      // n-block index of this fragment's 16 rows (all within one 32-row blk)
      const uint32_t nb = (uint32_t)(nTile * (BN / 32) + wn * 2 + (ni >> 1));
      const uint32_t hv = (kk + nb * r1) ^ r3;
      const uint32_t h = pow2 ? (hv & redMask) : (hv % numRedKb);
      const float* p = wBase + (size_t)(ni * 16) * redK + h * 32u;
      bF[2 * ni]     = *(const f32x4*)(p);
      bF[2 * ni + 1] = *(const f32x4*)(p + 4);
    }
  };

  auto stage = [&](const f32x4* rA) {
#pragma unroll
    for (int i = 0; i < 4; ++i) {
      bf16x4_t v;
#pragma unroll
      for (int j = 0; j < 4; ++j) v[j] = (__bf16)rA[i][j];
      *(bf16x4_t*)&As[(i * 32 + lRow) * LDSK + lCol] = v;
    }
  };

  f32x4 acc[4][4] = {};

  const int numKb = K / BK;
  const int kbN = numKb / KSPLIT;
  const int kb0 = kChunk * kbN;

  f32x4 a[4];
  loadA(kb0, a);
  loadBf(kb0);
  for (int i = 0; i < kbN; ++i) {
    wg_barrier_lds();                 // all waves' prev As reads consumed
    stage(a);                         // waits counted vmcnt for a-loads
    if (i + 1 < kbN) loadA(kb0 + i + 1, a);
    wg_barrier_lds();                 // As writes visible

    // convert this step's B frags (waits their vmcnt), then prefetch next
    bf16x8_t bb[4];
#pragma unroll
    for (int ni = 0; ni < 4; ++ni) {
      bf16x8_t t;
#pragma unroll
      for (int j = 0; j < 4; ++j) {
        t[j]     = (__bf16)bF[2 * ni][j];
        t[4 + j] = (__bf16)bF[2 * ni + 1][j];
      }
      bb[ni] = t;
    }
    if (i + 1 < kbN) loadBf(kb0 + i + 1);

    bf16x8_t af[4];
#pragma unroll
    for (int mi = 0; mi < 4; ++mi)
      af[mi] = *(const bf16x8_t*)&As[((wm << 6) + (mi << 4) + r16) * LDSK + e0];
#pragma unroll
    for (int mi = 0; mi < 4; ++mi)
#pragma unroll
      for (int ni = 0; ni < 4; ++ni)
        acc[mi][ni] = __builtin_amdgcn_mfma_f32_16x16x32_bf16(
            af[mi], bb[ni], acc[mi][ni], 0, 0, 0);
  }

  // epilogue: C/D map col(n)=lane&15, row(m)=(lane>>4)*4+reg; atomic accumulate
  const int mBase = mTile * BM + (wm << 6);
  const int nBase = nTile * BN + (wn << 6);
#pragma unroll
  for (int ni = 0; ni < 4; ++ni) {
    const int n = nBase + (ni << 4) + (lane & 15);
#pragma unroll
    for (int mi = 0; mi < 4; ++mi) {
      const int m0 = mBase + (mi << 4) + ((lane >> 4) << 2);
#pragma unroll
      for (int r = 0; r < 4; ++r)
        unsafeAtomicAdd(&Out[(size_t)(m0 + r) * N + n], acc[mi][ni][r]);
    }
  }
}

extern "C" void kernel_launch(void* const* d_in, const int* in_sizes, int n_in,
                              void* d_out, int out_size, void* d_ws, size_t ws_size,
                              hipStream_t stream) {
  const float* X = (const float*)d_in[0];
  const float* W = (const float*)d_in[1];
  const float* Bias = (const float*)d_in[2];
  const int* RN = (const int*)d_in[3];
  float* Out = (float*)d_out;

  const int N = in_sizes[2];             // 512
  const int M = out_size / N;            // 8192
  const int K = in_sizes[0] / M;         // 8192
  const int redK = in_sizes[1] / N;      // 1024
  const uint32_t numRedKb = (uint32_t)(redK / 32);  // 32

  const int total4 = out_size / 4;
  init_out<<<(total4 + 255) / 256, 256, 0, stream>>>(Out, Bias, N, total4);

  const int mTiles = M / BM;             // 64
  const int nTiles = N / BN;             // 4
  dim3 grid(mTiles * nTiles * KSPLIT), block(256);
  ssl_gemm<<<grid, block, 0, stream>>>(X, W, RN, Out,
                                       M, N, K, redK, numRedKb, mTiles, nTiles);
}